// Round 15
// baseline (739.511 us; speedup 1.0000x reference)
//
#include <hip/hip_runtime.h>
#include <hip/hip_bf16.h>

#define DHW (16 * 16 * 30)   // 7680 voxels per channel
#define NWCOL 7680           // hw columns = 120 f * 64 c
#define KTOT 30720           // hw rows
#define KSPLIT 96
#define KCH (KTOT / KSPLIT)  // 320 rows per block
#define NBLK (15 * KSPLIT)   // 1440 K2 blocks (~5.6/CU)
#define K1REP 40             // diagnostic rep count (this round only)
// ln(1024)/39
#define LN1024_OVER_39 0.17773004629742187f

// ---------------------------------------------------------------------------
// K1 v4 + x40 rep loop for profiling visibility (idempotent; rep-top barrier
// guards sW reuse). Structure identical to R14's 22-us kernel otherwise.
// ---------------------------------------------------------------------------
__global__ __launch_bounds__(512) void k1_conv(
    const float* __restrict__ feat0,
    const float* __restrict__ cw1, const float* __restrict__ cb1,
    const float* __restrict__ cw2, const float* __restrict__ cb2,
    const float* __restrict__ cw3, const float* __restrict__ cb3,
    float* __restrict__ fvecT)
{
    const int yi = blockIdx.x;   // 0..7
    const int zi = blockIdx.y;   // 0..7
    const int b  = blockIdx.z;   // 0..7
    const int t  = threadIdx.x;  // 0..511

    __shared__ float sIn[256][16];  // 16 KB
    __shared__ float sW[8192];      // 32 KB: weight tiles / partial sums
    __shared__ float sH1[128][16];  // 8 KB
    __shared__ float sH2[64][16];   // 4 KB

    const int og = t & 31;          // conv1/2 o-group
    const int wg = (t >> 5) & 3;    // conv1/2 w-group
    const int cs = t >> 7;          // c-split id 0..3
    const int u  = t & 127;         // (og,wg) unit id, shared across cs

    // ---- load input voxels once: feat0[b, c, 2zi, 2yi, 2w], w = 0..14 ----
    {
        const int w  = t & 15;
        const int cg = t >> 4;  // 0..31
        const float* base = feat0 + (size_t)b * 256 * DHW
                            + (2 * zi) * (16 * 30) + (2 * yi) * 30 + 2 * w;
        #pragma unroll
        for (int c0 = 0; c0 < 256; c0 += 32) {
            const int c = c0 + cg;
            sIn[c][w] = (w < 15) ? base[(size_t)c * DHW] : 0.f;
        }
    }

    #pragma unroll 1
    for (int rep = 0; rep < K1REP; ++rep) {
        __syncthreads();  // prior rep's sW readers done before re-staging

        // ================= conv1: 256 -> 128, relu =================
        {
            const int o0 = 4 * og, w0 = 4 * wg;
            float acc[4][4] = {};
            for (int c0 = 0; c0 < 256; c0 += 64) {
                const float4* src = (const float4*)(cw1 + c0 * 128);
                float4* dst = (float4*)sW;
                #pragma unroll
                for (int p = 0; p < 4; ++p) dst[t + 512 * p] = src[t + 512 * p];
                __syncthreads();
                #pragma unroll 4
                for (int j = 0; j < 16; ++j) {
                    const int cc = 16 * cs + j;
                    const float4 wv = *(const float4*)&sW[cc * 128 + o0];
                    const float4 xi = *(const float4*)&sIn[c0 + cc][w0];
                    acc[0][0] += xi.x * wv.x; acc[0][1] += xi.y * wv.x;
                    acc[0][2] += xi.z * wv.x; acc[0][3] += xi.w * wv.x;
                    acc[1][0] += xi.x * wv.y; acc[1][1] += xi.y * wv.y;
                    acc[1][2] += xi.z * wv.y; acc[1][3] += xi.w * wv.y;
                    acc[2][0] += xi.x * wv.z; acc[2][1] += xi.y * wv.z;
                    acc[2][2] += xi.z * wv.z; acc[2][3] += xi.w * wv.z;
                    acc[3][0] += xi.x * wv.w; acc[3][1] += xi.y * wv.w;
                    acc[3][2] += xi.z * wv.w; acc[3][3] += xi.w * wv.w;
                }
                __syncthreads();
            }
            if (cs > 0) {
                float4* pw = (float4*)&sW[(cs - 1) * 2048 + u * 16];
                #pragma unroll
                for (int j = 0; j < 4; ++j) pw[j] = *(const float4*)&acc[j][0];
            }
            __syncthreads();
            if (cs == 0) {
                #pragma unroll
                for (int s = 0; s < 3; ++s) {
                    const float4* pr = (const float4*)&sW[s * 2048 + u * 16];
                    #pragma unroll
                    for (int j = 0; j < 4; ++j) {
                        const float4 v = pr[j];
                        acc[j][0] += v.x; acc[j][1] += v.y;
                        acc[j][2] += v.z; acc[j][3] += v.w;
                    }
                }
                const float4 bv = *(const float4*)&cb1[o0];
                const float bb[4] = {bv.x, bv.y, bv.z, bv.w};
                #pragma unroll
                for (int j = 0; j < 4; ++j) {
                    float4 r;
                    r.x = fmaxf(acc[j][0] + bb[j], 0.f);
                    r.y = fmaxf(acc[j][1] + bb[j], 0.f);
                    r.z = fmaxf(acc[j][2] + bb[j], 0.f);
                    r.w = fmaxf(acc[j][3] + bb[j], 0.f);
                    *(float4*)&sH1[o0 + j][w0] = r;
                }
            }
            __syncthreads();
        }

        // ================= conv2: 128 -> 64, relu =================
        {
            const int o0 = 2 * og, w0 = 4 * wg;
            const float4* src = (const float4*)cw2;
            float4* dst = (float4*)sW;
            #pragma unroll
            for (int p = 0; p < 4; ++p) dst[t + 512 * p] = src[t + 512 * p];
            __syncthreads();

            float acc[2][4] = {};
            #pragma unroll 4
            for (int j = 0; j < 32; ++j) {
                const int cc = 32 * cs + j;
                const float2 wv = *(const float2*)&sW[cc * 64 + o0];
                const float4 xi = *(const float4*)&sH1[cc][w0];
                acc[0][0] += xi.x * wv.x; acc[0][1] += xi.y * wv.x;
                acc[0][2] += xi.z * wv.x; acc[0][3] += xi.w * wv.x;
                acc[1][0] += xi.x * wv.y; acc[1][1] += xi.y * wv.y;
                acc[1][2] += xi.z * wv.y; acc[1][3] += xi.w * wv.y;
            }
            __syncthreads();  // cw2 reads done -> sW reusable

            if (cs > 0) {
                float4* pw = (float4*)&sW[(cs - 1) * 1024 + u * 8];
                pw[0] = *(const float4*)&acc[0][0];
                pw[1] = *(const float4*)&acc[1][0];
            }
            ((float4*)&sW[4096])[t] = ((const float4*)cw3)[t];
            __syncthreads();

            if (cs == 0) {
                #pragma unroll
                for (int s = 0; s < 3; ++s) {
                    const float4* pr = (const float4*)&sW[s * 1024 + u * 8];
                    const float4 v0 = pr[0], v1 = pr[1];
                    acc[0][0] += v0.x; acc[0][1] += v0.y;
                    acc[0][2] += v0.z; acc[0][3] += v0.w;
                    acc[1][0] += v1.x; acc[1][1] += v1.y;
                    acc[1][2] += v1.z; acc[1][3] += v1.w;
                }
                const float2 bv = *(const float2*)&cb2[o0];
                float4 r0, r1;
                r0.x = fmaxf(acc[0][0] + bv.x, 0.f);
                r0.y = fmaxf(acc[0][1] + bv.x, 0.f);
                r0.z = fmaxf(acc[0][2] + bv.x, 0.f);
                r0.w = fmaxf(acc[0][3] + bv.x, 0.f);
                r1.x = fmaxf(acc[1][0] + bv.y, 0.f);
                r1.y = fmaxf(acc[1][1] + bv.y, 0.f);
                r1.z = fmaxf(acc[1][2] + bv.y, 0.f);
                r1.w = fmaxf(acc[1][3] + bv.y, 0.f);
                *(float4*)&sH2[o0][w0]     = r0;
                *(float4*)&sH2[o0 + 1][w0] = r1;
            }
            __syncthreads();
        }

        // ================= conv3: 64 -> 32, relu, scatter =================
        {
            const int og3 = t & 15, wg3 = (t >> 4) & 7, cs3 = t >> 7;
            const int o0 = 2 * og3, w0 = 2 * wg3;
            const int u3 = t & 127;
            float acc[2][2] = {};
            #pragma unroll 4
            for (int j = 0; j < 16; ++j) {
                const int cc = 16 * cs3 + j;
                const float2 wv = *(const float2*)&sW[4096 + cc * 32 + o0];
                const float2 xi = *(const float2*)&sH2[cc][w0];
                acc[0][0] += xi.x * wv.x; acc[0][1] += xi.y * wv.x;
                acc[1][0] += xi.x * wv.y; acc[1][1] += xi.y * wv.y;
            }
            if (cs3 > 0) {
                float4 v;
                v.x = acc[0][0]; v.y = acc[0][1];
                v.z = acc[1][0]; v.w = acc[1][1];
                *(float4*)&sW[(cs3 - 1) * 512 + u3 * 4] = v;
            }
            __syncthreads();
            if (cs3 == 0) {
                #pragma unroll
                for (int s = 0; s < 3; ++s) {
                    const float4 v = *(const float4*)&sW[s * 512 + u3 * 4];
                    acc[0][0] += v.x; acc[0][1] += v.y;
                    acc[1][0] += v.z; acc[1][1] += v.w;
                }
                const float2 bv = *(const float2*)&cb3[o0];
                #pragma unroll
                for (int oj = 0; oj < 2; ++oj) {
                    const int kbase = (((o0 + oj) * 8 + zi) * 8 + yi) * 15;
                    const float bj = oj ? bv.y : bv.x;
                    #pragma unroll
                    for (int wj = 0; wj < 2; ++wj) {
                        const int w = w0 + wj;
                        if (w < 15)
                            fvecT[(size_t)(kbase + w) * 8 + b] =
                                fmaxf(acc[oj][wj] + bj, 0.f);
                    }
                }
            }
        }
    }
}

// ---------------------------------------------------------------------------
// K2: column-panel streamer (R13-exact, measured ~144 us). 64-thread blocks,
// KSPLIT=96 -> 1440 blocks. sF = 10 KB LDS.
// ---------------------------------------------------------------------------
__global__ __launch_bounds__(64) void k2_stream(
    const float* __restrict__ hw,
    const float* __restrict__ fvecT,
    const float* __restrict__ coord,
    float* __restrict__ partial)
{
    __shared__ float zpart[512];
    __shared__ float sF[KCH * 8];  // this k-chunk's fvec, all 8 batches (10 KB)
    const int t = threadIdx.x;     // 0..63
    const int kbase = blockIdx.y * KCH;

    #pragma unroll
    for (int r = 0; r < 8; ++r) zpart[t * 8 + r] = 0.f;
    {
        const float4* fsrc = (const float4*)(fvecT + (size_t)kbase * 8);
        float4* fdst = (float4*)sF;
        #pragma unroll
        for (int p = 0; p < 10; ++p) fdst[t + 64 * p] = fsrc[t + 64 * p];
    }
    __syncthreads();

    const int jw = blockIdx.x * 512;
    const int j0 = jw + 4 * t;

    float accA[8][4] = {}, accB[8][4] = {};
    const float* hp = hw + (size_t)kbase * NWCOL + j0;

    #pragma unroll 4
    for (int kk = 0; kk < KCH; ++kk) {
        const float4 hA = *(const float4*)hp;
        const float4 hB = *(const float4*)(hp + 256);
        hp += NWCOL;
        const float4 f0 = *(const float4*)&sF[kk * 8];      // broadcast
        const float4 f1 = *(const float4*)&sF[kk * 8 + 4];  // broadcast
        const float fv[8] = {f0.x, f0.y, f0.z, f0.w, f1.x, f1.y, f1.z, f1.w};
        #pragma unroll
        for (int b = 0; b < 8; ++b) {
            accA[b][0] += fv[b] * hA.x;
            accA[b][1] += fv[b] * hA.y;
            accA[b][2] += fv[b] * hA.z;
            accA[b][3] += fv[b] * hA.w;
            accB[b][0] += fv[b] * hB.x;
            accB[b][1] += fv[b] * hB.y;
            accB[b][2] += fv[b] * hB.z;
            accB[b][3] += fv[b] * hB.w;
        }
    }

    // fold z[b,f] for both col-quads (same output cols cq.., different f)
    const int fA = 8 * blockIdx.x + (t >> 4);
    const int fB = fA + 4;
    const int i3A = fA / 40, qA = fA - 40 * i3A;
    const int i3B = fB / 40, qB = fB - 40 * i3B;
    const float freqA = __expf((float)qA * LN1024_OVER_39);
    const float freqB = __expf((float)qB * LN1024_OVER_39);
    const int cq = 4 * (t & 15);

    #pragma unroll
    for (int b = 0; b < 8; ++b) {
        const float zvA = coord[b * 3 + i3A] * freqA;
        const float zvB = coord[b * 3 + i3B] * freqB;
        #pragma unroll
        for (int e = 0; e < 4; ++e)
            atomicAdd(&zpart[b * 64 + cq + e],
                      zvA * accA[b][e] + zvB * accB[b][e]);
    }
    __syncthreads();

    const int bid = blockIdx.x + 15 * blockIdx.y;
    float4* pp = (float4*)(partial + (size_t)bid * 512);
    pp[t]      = ((const float4*)zpart)[t];
    pp[t + 64] = ((const float4*)zpart)[t + 64];
}

// ---------------------------------------------------------------------------
// K2b: reduce partial[1440][512] -> z1[512]. 64 blocks x 256 threads.
// ---------------------------------------------------------------------------
__global__ __launch_bounds__(256) void k2b_reduce(
    const float* __restrict__ partial, float* __restrict__ z1)
{
    __shared__ float s[256];
    const int t = threadIdx.x;
    const int o = blockIdx.x * 8 + (t & 7);  // output element
    float sum = 0.f;
    for (int blk = t >> 3; blk < NBLK; blk += 32)
        sum += partial[(size_t)blk * 512 + o];
    s[t] = sum;
    __syncthreads();
    if (t < 8) {
        float tot = 0.f;
        #pragma unroll
        for (int i = 0; i < 32; ++i) tot += s[t + 8 * i];
        z1[blockIdx.x * 8 + t] = tot;
    }
}

// ---------------------------------------------------------------------------
// K3: hb-bias term + MLP tail, all weights LDS-staged (coalesced float4).
// One block, 512 threads = (b=8, c=64).
// ---------------------------------------------------------------------------
__global__ __launch_bounds__(512) void k3_tail(
    const float* __restrict__ z1acc, const float* __restrict__ coord,
    const float* __restrict__ hb,
    const float* __restrict__ w1, const float* __restrict__ b1,
    const float* __restrict__ w2, const float* __restrict__ b2,
    const float* __restrict__ wo, const float* __restrict__ bo,
    float* __restrict__ out)
{
    __shared__ float shb[7680];  // 30 KB
    __shared__ float sw1[4096];  // 16 KB
    __shared__ float sw2[4096];  // 16 KB
    __shared__ float swo[192];
    __shared__ float sz[8][64];
    __shared__ float s2[8][64];
    __shared__ float sfreq[40];
    __shared__ float sc[24];
    const int t = threadIdx.x;

    #pragma unroll
    for (int p = 0; p < 4; ++p) {
        const int idx = t + 512 * p;
        if (idx < 1920) ((float4*)shb)[idx] = ((const float4*)hb)[idx];
    }
    ((float4*)sw1)[t]       = ((const float4*)w1)[t];
    ((float4*)sw1)[t + 512] = ((const float4*)w1)[t + 512];
    ((float4*)sw2)[t]       = ((const float4*)w2)[t];
    ((float4*)sw2)[t + 512] = ((const float4*)w2)[t + 512];
    if (t < 48) ((float4*)swo)[t] = ((const float4*)wo)[t];
    if (t < 40) sfreq[t] = __expf((float)t * LN1024_OVER_39);
    if (t < 24) sc[t] = coord[t];
    __syncthreads();

    const int b = t >> 6, c = t & 63;

    float a = z1acc[t];
    #pragma unroll
    for (int i = 0; i < 3; ++i) {
        const float cv = sc[b * 3 + i];
        #pragma unroll 8
        for (int q = 0; q < 40; ++q)
            a += cv * sfreq[q] * shb[(i * 40 + q) * 64 + c];
    }
    sz[b][c] = a;  // no activation on modulated layer 0
    __syncthreads();

    float a1 = b1[c];
    #pragma unroll 8
    for (int cc = 0; cc < 64; ++cc) a1 += sz[b][cc] * sw1[cc * 64 + c];
    s2[b][c] = fmaxf(a1, 0.f);
    __syncthreads();

    float a2 = b2[c];
    #pragma unroll 8
    for (int cc = 0; cc < 64; ++cc) a2 += s2[b][cc] * sw2[cc * 64 + c];
    sz[b][c] = fmaxf(a2, 0.f);
    __syncthreads();

    if (t < 24) {
        const int bb = t / 3, i = t - bb * 3;
        float o = bo[i];
        #pragma unroll 8
        for (int cc = 0; cc < 64; ++cc) o += sz[bb][cc] * swo[cc * 3 + i];
        out[t] = o;
    }
}

// ---------------------------------------------------------------------------
extern "C" void kernel_launch(void* const* d_in, const int* in_sizes, int n_in,
                              void* d_out, int out_size, void* d_ws, size_t ws_size,
                              hipStream_t stream)
{
    const float* coord = (const float*)d_in[0];
    const float* feat0 = (const float*)d_in[1];
    const float* cw1 = (const float*)d_in[2];
    const float* cb1 = (const float*)d_in[3];
    const float* cw2 = (const float*)d_in[4];
    const float* cb2 = (const float*)d_in[5];
    const float* cw3 = (const float*)d_in[6];
    const float* cb3 = (const float*)d_in[7];
    const float* hw  = (const float*)d_in[8];
    const float* hb  = (const float*)d_in[9];
    const float* w1  = (const float*)d_in[10];
    const float* b1  = (const float*)d_in[11];
    const float* w2  = (const float*)d_in[12];
    const float* b2  = (const float*)d_in[13];
    const float* wo  = (const float*)d_in[14];
    const float* bo  = (const float*)d_in[15];
    float* out = (float*)d_out;

    float* fvecT   = (float*)d_ws;                  // 30720*8 floats = 983 KB
    float* partial = fvecT + (size_t)KTOT * 8;      // 1440*512 floats = 2.95 MB
    float* z1      = partial + (size_t)NBLK * 512;  // 512 floats

    k1_conv<<<dim3(8, 8, 8), 512, 0, stream>>>(feat0, cw1, cb1, cw2, cb2,
                                               cw3, cb3, fvecT);
    k2_stream<<<dim3(15, KSPLIT), 64, 0, stream>>>(hw, fvecT, coord, partial);
    k2b_reduce<<<64, 256, 0, stream>>>(partial, z1);
    k3_tail<<<1, 512, 0, stream>>>(z1, coord, hb, w1, b1, w2, b2, wo, bo, out);
}

// Round 16
// 221.607 us; speedup vs baseline: 3.3370x; 3.3370x over previous
//
#include <hip/hip_runtime.h>
#include <hip/hip_bf16.h>

#define DHW (16 * 16 * 30)   // 7680 voxels per channel
#define NWCOL 7680           // hw columns = 120 f * 64 c
#define KTOT 30720           // hw rows
#define KSPLIT 96
#define KCH (KTOT / KSPLIT)  // 320 rows per block
#define NBLK (15 * KSPLIT)   // 1440 K2 blocks (~5.6/CU)
// ln(1024)/39
#define LN1024_OVER_39 0.17773004629742187f

// ---------------------------------------------------------------------------
// K1 v5: v4 structure with CONFLICT-FREE LDS layouts (R15 probe: 3.44e7
// SQ_LDS_BANK_CONFLICT, VALUBusy 41% -> conflict-bound, not issue-bound).
//  - activations transposed+padded: sH1T[16 w][132 o], sH2T[16 w][68 o]
//    (epilogue writes o-contiguous: lane stride 4 words = balanced;
//     next-layer reads: broadcast rows, chunked along o)
//  - partial parks in [comp][u] layout: lane stride 1 word
// One 512-thread block per (b, zi, yi); ~61 KB LDS -> 2 blocks/CU.
// Writes fvecT[k][b], k = ((ch*8+zi)*8+yi)*15 + w   (torch flatten order)
// ---------------------------------------------------------------------------
__global__ __launch_bounds__(512) void k1_conv(
    const float* __restrict__ feat0,
    const float* __restrict__ cw1, const float* __restrict__ cb1,
    const float* __restrict__ cw2, const float* __restrict__ cb2,
    const float* __restrict__ cw3, const float* __restrict__ cb3,
    float* __restrict__ fvecT)
{
    const int yi = blockIdx.x;   // 0..7
    const int zi = blockIdx.y;   // 0..7
    const int b  = blockIdx.z;   // 0..7
    const int t  = threadIdx.x;  // 0..511

    __shared__ float sIn[256][16];    // 16 KB
    __shared__ float sW[8192];        // 32 KB: weight tiles / parks
    __shared__ float sH1T[16][132];   // 8.25 KB  [w][o1], +4 pad
    __shared__ float sH2T[16][68];    // 4.25 KB  [w][o2], +4 pad

    const int og = t & 31;          // conv1/2 o-group
    const int wg = (t >> 5) & 3;    // conv1/2 w-group
    const int cs = t >> 7;          // c-split id 0..3
    const int u  = t & 127;         // (og,wg) unit id, shared across cs

    // ---- load input voxels: feat0[b, c, 2zi, 2yi, 2w], w = 0..14 ----
    {
        const int w  = t & 15;
        const int cg = t >> 4;  // 0..31
        const float* base = feat0 + (size_t)b * 256 * DHW
                            + (2 * zi) * (16 * 30) + (2 * yi) * 30 + 2 * w;
        #pragma unroll
        for (int c0 = 0; c0 < 256; c0 += 32) {
            const int c = c0 + cg;
            sIn[c][w] = (w < 15) ? base[(size_t)c * DHW] : 0.f;
        }
    }

    // ================= conv1: 256 -> 128, relu =================
    {
        const int o0 = 4 * og, w0 = 4 * wg;
        float acc[4][4] = {};  // [oj][wi]
        for (int c0 = 0; c0 < 256; c0 += 64) {
            // stage 64x128 tile of cw1 (lane stride 4 words: balanced)
            const float4* src = (const float4*)(cw1 + c0 * 128);
            float4* dst = (float4*)sW;
            #pragma unroll
            for (int p = 0; p < 4; ++p) dst[t + 512 * p] = src[t + 512 * p];
            __syncthreads();
            #pragma unroll 4
            for (int j = 0; j < 16; ++j) {
                const int cc = 16 * cs + j;
                const float4 wv = *(const float4*)&sW[cc * 128 + o0];
                const float4 xi = *(const float4*)&sIn[c0 + cc][w0];
                acc[0][0] += xi.x * wv.x; acc[0][1] += xi.y * wv.x;
                acc[0][2] += xi.z * wv.x; acc[0][3] += xi.w * wv.x;
                acc[1][0] += xi.x * wv.y; acc[1][1] += xi.y * wv.y;
                acc[1][2] += xi.z * wv.y; acc[1][3] += xi.w * wv.y;
                acc[2][0] += xi.x * wv.z; acc[2][1] += xi.y * wv.z;
                acc[2][2] += xi.z * wv.z; acc[2][3] += xi.w * wv.z;
                acc[3][0] += xi.x * wv.w; acc[3][1] += xi.y * wv.w;
                acc[3][2] += xi.z * wv.w; acc[3][3] += xi.w * wv.w;
            }
            __syncthreads();
        }
        // park partials: [comp 16][u 128] layout, lane stride 1 (no conflicts)
        if (cs > 0) {
            float* pk = &sW[(cs - 1) * 2048];
            #pragma unroll
            for (int oj = 0; oj < 4; ++oj)
                #pragma unroll
                for (int wi = 0; wi < 4; ++wi)
                    pk[(oj * 4 + wi) * 128 + u] = acc[oj][wi];
        }
        __syncthreads();
        if (cs == 0) {
            #pragma unroll
            for (int s = 0; s < 3; ++s) {
                const float* pk = &sW[s * 2048];
                #pragma unroll
                for (int oj = 0; oj < 4; ++oj)
                    #pragma unroll
                    for (int wi = 0; wi < 4; ++wi)
                        acc[oj][wi] += pk[(oj * 4 + wi) * 128 + u];
            }
            const float4 bv = *(const float4*)&cb1[o0];
            const float bb[4] = {bv.x, bv.y, bv.z, bv.w};
            // write transposed: row w, o-contiguous float4 (stride 4: balanced)
            #pragma unroll
            for (int wi = 0; wi < 4; ++wi) {
                float4 r;
                r.x = fmaxf(acc[0][wi] + bb[0], 0.f);
                r.y = fmaxf(acc[1][wi] + bb[1], 0.f);
                r.z = fmaxf(acc[2][wi] + bb[2], 0.f);
                r.w = fmaxf(acc[3][wi] + bb[3], 0.f);
                *(float4*)&sH1T[w0 + wi][o0] = r;
            }
        }
        __syncthreads();
    }

    // ================= conv2: 128 -> 64, relu =================
    {
        const int o0 = 2 * og, w0 = 4 * wg;
        // stage cw2 fully (128x64)
        const float4* src = (const float4*)cw2;
        float4* dst = (float4*)sW;
        #pragma unroll
        for (int p = 0; p < 4; ++p) dst[t + 512 * p] = src[t + 512 * p];
        __syncthreads();

        float acc[2][4] = {};  // [oj][wi]
        #pragma unroll 2
        for (int jc = 0; jc < 8; ++jc) {
            const int cc0 = 32 * cs + 4 * jc;
            // xi rows: broadcast (2 addrs/wave); o-chunked float4
            float4 xiw[4];
            #pragma unroll
            for (int wi = 0; wi < 4; ++wi)
                xiw[wi] = *(const float4*)&sH1T[w0 + wi][cc0];
            #pragma unroll
            for (int k = 0; k < 4; ++k) {
                const float2 wv = *(const float2*)&sW[(cc0 + k) * 64 + o0];
                const float xk[4] = {k == 0 ? xiw[0].x : k == 1 ? xiw[0].y : k == 2 ? xiw[0].z : xiw[0].w,
                                     k == 0 ? xiw[1].x : k == 1 ? xiw[1].y : k == 2 ? xiw[1].z : xiw[1].w,
                                     k == 0 ? xiw[2].x : k == 1 ? xiw[2].y : k == 2 ? xiw[2].z : xiw[2].w,
                                     k == 0 ? xiw[3].x : k == 1 ? xiw[3].y : k == 2 ? xiw[3].z : xiw[3].w};
                #pragma unroll
                for (int wi = 0; wi < 4; ++wi) {
                    acc[0][wi] += xk[wi] * wv.x;
                    acc[1][wi] += xk[wi] * wv.y;
                }
            }
        }
        __syncthreads();  // cw2 reads done -> sW reusable

        if (cs > 0) {
            float* pk = &sW[(cs - 1) * 1024];
            #pragma unroll
            for (int oj = 0; oj < 2; ++oj)
                #pragma unroll
                for (int wi = 0; wi < 4; ++wi)
                    pk[(oj * 4 + wi) * 128 + u] = acc[oj][wi];
        }
        // stage cw3 (2048 floats) into sW[4096..6143] — disjoint region
        ((float4*)&sW[4096])[t] = ((const float4*)cw3)[t];
        __syncthreads();

        if (cs == 0) {
            #pragma unroll
            for (int s = 0; s < 3; ++s) {
                const float* pk = &sW[s * 1024];
                #pragma unroll
                for (int oj = 0; oj < 2; ++oj)
                    #pragma unroll
                    for (int wi = 0; wi < 4; ++wi)
                        acc[oj][wi] += pk[(oj * 4 + wi) * 128 + u];
            }
            const float2 bv = *(const float2*)&cb2[o0];
            #pragma unroll
            for (int wi = 0; wi < 4; ++wi) {
                float2 r;
                r.x = fmaxf(acc[0][wi] + bv.x, 0.f);
                r.y = fmaxf(acc[1][wi] + bv.y, 0.f);
                *(float2*)&sH2T[w0 + wi][o0] = r;
            }
        }
        __syncthreads();
    }

    // ================= conv3: 64 -> 32, relu, scatter =================
    {
        const int og3 = t & 15, wg3 = (t >> 4) & 7, cs3 = t >> 7;
        const int o0 = 2 * og3, w0 = 2 * wg3;   // w0 in {0..14}
        const int u3 = t & 127;
        float acc[2][2] = {};  // [oj][wi]
        #pragma unroll 2
        for (int jc = 0; jc < 8; ++jc) {
            const int cc0 = 16 * cs3 + 2 * jc;
            const float2 xw0 = *(const float2*)&sH2T[w0][cc0];
            const float2 xw1 = *(const float2*)&sH2T[w0 + 1][cc0];
            const float2 wv0 = *(const float2*)&sW[4096 + cc0 * 32 + o0];
            const float2 wv1 = *(const float2*)&sW[4096 + (cc0 + 1) * 32 + o0];
            acc[0][0] += xw0.x * wv0.x; acc[0][1] += xw1.x * wv0.x;
            acc[1][0] += xw0.x * wv0.y; acc[1][1] += xw1.x * wv0.y;
            acc[0][0] += xw0.y * wv1.x; acc[0][1] += xw1.y * wv1.x;
            acc[1][0] += xw0.y * wv1.y; acc[1][1] += xw1.y * wv1.y;
        }
        if (cs3 > 0) {
            float* pk = &sW[(cs3 - 1) * 512];
            #pragma unroll
            for (int oj = 0; oj < 2; ++oj)
                #pragma unroll
                for (int wi = 0; wi < 2; ++wi)
                    pk[(oj * 2 + wi) * 128 + u3] = acc[oj][wi];
        }
        __syncthreads();
        if (cs3 == 0) {
            #pragma unroll
            for (int s = 0; s < 3; ++s) {
                const float* pk = &sW[s * 512];
                #pragma unroll
                for (int oj = 0; oj < 2; ++oj)
                    #pragma unroll
                    for (int wi = 0; wi < 2; ++wi)
                        acc[oj][wi] += pk[(oj * 2 + wi) * 128 + u3];
            }
            const float2 bv = *(const float2*)&cb3[o0];
            #pragma unroll
            for (int oj = 0; oj < 2; ++oj) {
                const int kbase = (((o0 + oj) * 8 + zi) * 8 + yi) * 15;
                const float bj = oj ? bv.y : bv.x;
                #pragma unroll
                for (int wi = 0; wi < 2; ++wi) {
                    const int w = w0 + wi;
                    if (w < 15)
                        fvecT[(size_t)(kbase + w) * 8 + b] =
                            fmaxf(acc[oj][wi] + bj, 0.f);
                }
            }
        }
    }
}

// ---------------------------------------------------------------------------
// K2: column-panel streamer (R13-exact, measured ~144 us). 64-thread blocks,
// KSPLIT=96 -> 1440 blocks. sF = 10 KB LDS.
// ---------------------------------------------------------------------------
__global__ __launch_bounds__(64) void k2_stream(
    const float* __restrict__ hw,
    const float* __restrict__ fvecT,
    const float* __restrict__ coord,
    float* __restrict__ partial)
{
    __shared__ float zpart[512];
    __shared__ float sF[KCH * 8];  // this k-chunk's fvec, all 8 batches (10 KB)
    const int t = threadIdx.x;     // 0..63
    const int kbase = blockIdx.y * KCH;

    #pragma unroll
    for (int r = 0; r < 8; ++r) zpart[t * 8 + r] = 0.f;
    {
        const float4* fsrc = (const float4*)(fvecT + (size_t)kbase * 8);
        float4* fdst = (float4*)sF;
        #pragma unroll
        for (int p = 0; p < 10; ++p) fdst[t + 64 * p] = fsrc[t + 64 * p];
    }
    __syncthreads();

    const int jw = blockIdx.x * 512;
    const int j0 = jw + 4 * t;

    float accA[8][4] = {}, accB[8][4] = {};
    const float* hp = hw + (size_t)kbase * NWCOL + j0;

    #pragma unroll 4
    for (int kk = 0; kk < KCH; ++kk) {
        const float4 hA = *(const float4*)hp;
        const float4 hB = *(const float4*)(hp + 256);
        hp += NWCOL;
        const float4 f0 = *(const float4*)&sF[kk * 8];      // broadcast
        const float4 f1 = *(const float4*)&sF[kk * 8 + 4];  // broadcast
        const float fv[8] = {f0.x, f0.y, f0.z, f0.w, f1.x, f1.y, f1.z, f1.w};
        #pragma unroll
        for (int b = 0; b < 8; ++b) {
            accA[b][0] += fv[b] * hA.x;
            accA[b][1] += fv[b] * hA.y;
            accA[b][2] += fv[b] * hA.z;
            accA[b][3] += fv[b] * hA.w;
            accB[b][0] += fv[b] * hB.x;
            accB[b][1] += fv[b] * hB.y;
            accB[b][2] += fv[b] * hB.z;
            accB[b][3] += fv[b] * hB.w;
        }
    }

    // fold z[b,f] for both col-quads (same output cols cq.., different f)
    const int fA = 8 * blockIdx.x + (t >> 4);
    const int fB = fA + 4;
    const int i3A = fA / 40, qA = fA - 40 * i3A;
    const int i3B = fB / 40, qB = fB - 40 * i3B;
    const float freqA = __expf((float)qA * LN1024_OVER_39);
    const float freqB = __expf((float)qB * LN1024_OVER_39);
    const int cq = 4 * (t & 15);

    #pragma unroll
    for (int b = 0; b < 8; ++b) {
        const float zvA = coord[b * 3 + i3A] * freqA;
        const float zvB = coord[b * 3 + i3B] * freqB;
        #pragma unroll
        for (int e = 0; e < 4; ++e)
            atomicAdd(&zpart[b * 64 + cq + e],
                      zvA * accA[b][e] + zvB * accB[b][e]);
    }
    __syncthreads();

    const int bid = blockIdx.x + 15 * blockIdx.y;
    float4* pp = (float4*)(partial + (size_t)bid * 512);
    pp[t]      = ((const float4*)zpart)[t];
    pp[t + 64] = ((const float4*)zpart)[t + 64];
}

// ---------------------------------------------------------------------------
// K2b: reduce partial[1440][512] -> z1[512]. 64 blocks x 256 threads.
// ---------------------------------------------------------------------------
__global__ __launch_bounds__(256) void k2b_reduce(
    const float* __restrict__ partial, float* __restrict__ z1)
{
    __shared__ float s[256];
    const int t = threadIdx.x;
    const int o = blockIdx.x * 8 + (t & 7);  // output element
    float sum = 0.f;
    for (int blk = t >> 3; blk < NBLK; blk += 32)
        sum += partial[(size_t)blk * 512 + o];
    s[t] = sum;
    __syncthreads();
    if (t < 8) {
        float tot = 0.f;
        #pragma unroll
        for (int i = 0; i < 32; ++i) tot += s[t + 8 * i];
        z1[blockIdx.x * 8 + t] = tot;
    }
}

// ---------------------------------------------------------------------------
// K3: hb-bias term + MLP tail, all weights LDS-staged (coalesced float4).
// One block, 512 threads = (b=8, c=64).
// ---------------------------------------------------------------------------
__global__ __launch_bounds__(512) void k3_tail(
    const float* __restrict__ z1acc, const float* __restrict__ coord,
    const float* __restrict__ hb,
    const float* __restrict__ w1, const float* __restrict__ b1,
    const float* __restrict__ w2, const float* __restrict__ b2,
    const float* __restrict__ wo, const float* __restrict__ bo,
    float* __restrict__ out)
{
    __shared__ float shb[7680];  // 30 KB
    __shared__ float sw1[4096];  // 16 KB
    __shared__ float sw2[4096];  // 16 KB
    __shared__ float swo[192];
    __shared__ float sz[8][64];
    __shared__ float s2[8][64];
    __shared__ float sfreq[40];
    __shared__ float sc[24];
    const int t = threadIdx.x;

    #pragma unroll
    for (int p = 0; p < 4; ++p) {
        const int idx = t + 512 * p;
        if (idx < 1920) ((float4*)shb)[idx] = ((const float4*)hb)[idx];
    }
    ((float4*)sw1)[t]       = ((const float4*)w1)[t];
    ((float4*)sw1)[t + 512] = ((const float4*)w1)[t + 512];
    ((float4*)sw2)[t]       = ((const float4*)w2)[t];
    ((float4*)sw2)[t + 512] = ((const float4*)w2)[t + 512];
    if (t < 48) ((float4*)swo)[t] = ((const float4*)wo)[t];
    if (t < 40) sfreq[t] = __expf((float)t * LN1024_OVER_39);
    if (t < 24) sc[t] = coord[t];
    __syncthreads();

    const int b = t >> 6, c = t & 63;

    float a = z1acc[t];
    #pragma unroll
    for (int i = 0; i < 3; ++i) {
        const float cv = sc[b * 3 + i];
        #pragma unroll 8
        for (int q = 0; q < 40; ++q)
            a += cv * sfreq[q] * shb[(i * 40 + q) * 64 + c];
    }
    sz[b][c] = a;  // no activation on modulated layer 0
    __syncthreads();

    float a1 = b1[c];
    #pragma unroll 8
    for (int cc = 0; cc < 64; ++cc) a1 += sz[b][cc] * sw1[cc * 64 + c];
    s2[b][c] = fmaxf(a1, 0.f);
    __syncthreads();

    float a2 = b2[c];
    #pragma unroll 8
    for (int cc = 0; cc < 64; ++cc) a2 += s2[b][cc] * sw2[cc * 64 + c];
    sz[b][c] = fmaxf(a2, 0.f);
    __syncthreads();

    if (t < 24) {
        const int bb = t / 3, i = t - bb * 3;
        float o = bo[i];
        #pragma unroll 8
        for (int cc = 0; cc < 64; ++cc) o += sz[bb][cc] * swo[cc * 3 + i];
        out[t] = o;
    }
}

// ---------------------------------------------------------------------------
extern "C" void kernel_launch(void* const* d_in, const int* in_sizes, int n_in,
                              void* d_out, int out_size, void* d_ws, size_t ws_size,
                              hipStream_t stream)
{
    const float* coord = (const float*)d_in[0];
    const float* feat0 = (const float*)d_in[1];
    const float* cw1 = (const float*)d_in[2];
    const float* cb1 = (const float*)d_in[3];
    const float* cw2 = (const float*)d_in[4];
    const float* cb2 = (const float*)d_in[5];
    const float* cw3 = (const float*)d_in[6];
    const float* cb3 = (const float*)d_in[7];
    const float* hw  = (const float*)d_in[8];
    const float* hb  = (const float*)d_in[9];
    const float* w1  = (const float*)d_in[10];
    const float* b1  = (const float*)d_in[11];
    const float* w2  = (const float*)d_in[12];
    const float* b2  = (const float*)d_in[13];
    const float* wo  = (const float*)d_in[14];
    const float* bo  = (const float*)d_in[15];
    float* out = (float*)d_out;

    float* fvecT   = (float*)d_ws;                  // 30720*8 floats = 983 KB
    float* partial = fvecT + (size_t)KTOT * 8;      // 1440*512 floats = 2.95 MB
    float* z1      = partial + (size_t)NBLK * 512;  // 512 floats

    k1_conv<<<dim3(8, 8, 8), 512, 0, stream>>>(feat0, cw1, cb1, cw2, cb2,
                                               cw3, cb3, fvecT);
    k2_stream<<<dim3(15, KSPLIT), 64, 0, stream>>>(hw, fvecT, coord, partial);
    k2b_reduce<<<64, 256, 0, stream>>>(partial, z1);
    k3_tail<<<1, 512, 0, stream>>>(z1, coord, hb, w1, b1, w2, b2, wo, bo, out);
}

// Round 17
// 215.077 us; speedup vs baseline: 3.4384x; 1.0304x over previous
//
#include <hip/hip_runtime.h>
#include <hip/hip_bf16.h>

#define DHW (16 * 16 * 30)   // 7680 voxels per channel
#define NWCOL 7680           // hw columns = 120 f * 64 c
#define KTOT 30720           // hw rows
#define KSPLIT 80
#define KCH (KTOT / KSPLIT)  // 384 rows per block
#define NBLK (15 * KSPLIT)   // 1200 K2 blocks (~4.7/CU)
// ln(1024)/39
#define LN1024_OVER_39 0.17773004629742187f

// ---------------------------------------------------------------------------
// K1 (R14 v4, measured ~22 us — best of 5 variants). Register-tiled 4o x 4w,
// c-split 4 ways, LDS partial reduction. Also zeroes the k2bc counter.
// Writes fvecT[k][b], k = ((ch*8+zi)*8+yi)*15 + w   (torch flatten order)
// ---------------------------------------------------------------------------
__global__ __launch_bounds__(512) void k1_conv(
    const float* __restrict__ feat0,
    const float* __restrict__ cw1, const float* __restrict__ cb1,
    const float* __restrict__ cw2, const float* __restrict__ cb2,
    const float* __restrict__ cw3, const float* __restrict__ cb3,
    float* __restrict__ fvecT, int* __restrict__ counter)
{
    const int yi = blockIdx.x;   // 0..7
    const int zi = blockIdx.y;   // 0..7
    const int b  = blockIdx.z;   // 0..7
    const int t  = threadIdx.x;  // 0..511

    if (t == 0 && yi == 0 && zi == 0 && b == 0) *counter = 0;

    __shared__ float sIn[256][16];  // 16 KB
    __shared__ float sW[8192];      // 32 KB: weight tiles / partial sums
    __shared__ float sH1[128][16];  // 8 KB
    __shared__ float sH2[64][16];   // 4 KB

    const int og = t & 31;          // conv1/2 o-group
    const int wg = (t >> 5) & 3;    // conv1/2 w-group
    const int cs = t >> 7;          // c-split id 0..3
    const int u  = t & 127;         // (og,wg) unit id, shared across cs

    // ---- load input voxels: feat0[b, c, 2zi, 2yi, 2w], w = 0..14 ----
    {
        const int w  = t & 15;
        const int cg = t >> 4;  // 0..31
        const float* base = feat0 + (size_t)b * 256 * DHW
                            + (2 * zi) * (16 * 30) + (2 * yi) * 30 + 2 * w;
        #pragma unroll
        for (int c0 = 0; c0 < 256; c0 += 32) {
            const int c = c0 + cg;
            sIn[c][w] = (w < 15) ? base[(size_t)c * DHW] : 0.f;
        }
    }

    // ================= conv1: 256 -> 128, relu =================
    {
        const int o0 = 4 * og, w0 = 4 * wg;
        float acc[4][4] = {};
        for (int c0 = 0; c0 < 256; c0 += 64) {
            const float4* src = (const float4*)(cw1 + c0 * 128);
            float4* dst = (float4*)sW;
            #pragma unroll
            for (int p = 0; p < 4; ++p) dst[t + 512 * p] = src[t + 512 * p];
            __syncthreads();
            #pragma unroll 4
            for (int j = 0; j < 16; ++j) {
                const int cc = 16 * cs + j;
                const float4 wv = *(const float4*)&sW[cc * 128 + o0];
                const float4 xi = *(const float4*)&sIn[c0 + cc][w0];
                acc[0][0] += xi.x * wv.x; acc[0][1] += xi.y * wv.x;
                acc[0][2] += xi.z * wv.x; acc[0][3] += xi.w * wv.x;
                acc[1][0] += xi.x * wv.y; acc[1][1] += xi.y * wv.y;
                acc[1][2] += xi.z * wv.y; acc[1][3] += xi.w * wv.y;
                acc[2][0] += xi.x * wv.z; acc[2][1] += xi.y * wv.z;
                acc[2][2] += xi.z * wv.z; acc[2][3] += xi.w * wv.z;
                acc[3][0] += xi.x * wv.w; acc[3][1] += xi.y * wv.w;
                acc[3][2] += xi.z * wv.w; acc[3][3] += xi.w * wv.w;
            }
            __syncthreads();
        }
        if (cs > 0) {
            float4* pw = (float4*)&sW[(cs - 1) * 2048 + u * 16];
            #pragma unroll
            for (int j = 0; j < 4; ++j) pw[j] = *(const float4*)&acc[j][0];
        }
        __syncthreads();
        if (cs == 0) {
            #pragma unroll
            for (int s = 0; s < 3; ++s) {
                const float4* pr = (const float4*)&sW[s * 2048 + u * 16];
                #pragma unroll
                for (int j = 0; j < 4; ++j) {
                    const float4 v = pr[j];
                    acc[j][0] += v.x; acc[j][1] += v.y;
                    acc[j][2] += v.z; acc[j][3] += v.w;
                }
            }
            const float4 bv = *(const float4*)&cb1[o0];
            const float bb[4] = {bv.x, bv.y, bv.z, bv.w};
            #pragma unroll
            for (int j = 0; j < 4; ++j) {
                float4 r;
                r.x = fmaxf(acc[j][0] + bb[j], 0.f);
                r.y = fmaxf(acc[j][1] + bb[j], 0.f);
                r.z = fmaxf(acc[j][2] + bb[j], 0.f);
                r.w = fmaxf(acc[j][3] + bb[j], 0.f);
                *(float4*)&sH1[o0 + j][w0] = r;
            }
        }
        __syncthreads();
    }

    // ================= conv2: 128 -> 64, relu =================
    {
        const int o0 = 2 * og, w0 = 4 * wg;
        const float4* src = (const float4*)cw2;
        float4* dst = (float4*)sW;
        #pragma unroll
        for (int p = 0; p < 4; ++p) dst[t + 512 * p] = src[t + 512 * p];
        __syncthreads();

        float acc[2][4] = {};
        #pragma unroll 4
        for (int j = 0; j < 32; ++j) {
            const int cc = 32 * cs + j;
            const float2 wv = *(const float2*)&sW[cc * 64 + o0];
            const float4 xi = *(const float4*)&sH1[cc][w0];
            acc[0][0] += xi.x * wv.x; acc[0][1] += xi.y * wv.x;
            acc[0][2] += xi.z * wv.x; acc[0][3] += xi.w * wv.x;
            acc[1][0] += xi.x * wv.y; acc[1][1] += xi.y * wv.y;
            acc[1][2] += xi.z * wv.y; acc[1][3] += xi.w * wv.y;
        }
        __syncthreads();  // cw2 reads done -> sW reusable

        if (cs > 0) {
            float4* pw = (float4*)&sW[(cs - 1) * 1024 + u * 8];
            pw[0] = *(const float4*)&acc[0][0];
            pw[1] = *(const float4*)&acc[1][0];
        }
        ((float4*)&sW[4096])[t] = ((const float4*)cw3)[t];
        __syncthreads();

        if (cs == 0) {
            #pragma unroll
            for (int s = 0; s < 3; ++s) {
                const float4* pr = (const float4*)&sW[s * 1024 + u * 8];
                const float4 v0 = pr[0], v1 = pr[1];
                acc[0][0] += v0.x; acc[0][1] += v0.y;
                acc[0][2] += v0.z; acc[0][3] += v0.w;
                acc[1][0] += v1.x; acc[1][1] += v1.y;
                acc[1][2] += v1.z; acc[1][3] += v1.w;
            }
            const float2 bv = *(const float2*)&cb2[o0];
            float4 r0, r1;
            r0.x = fmaxf(acc[0][0] + bv.x, 0.f);
            r0.y = fmaxf(acc[0][1] + bv.x, 0.f);
            r0.z = fmaxf(acc[0][2] + bv.x, 0.f);
            r0.w = fmaxf(acc[0][3] + bv.x, 0.f);
            r1.x = fmaxf(acc[1][0] + bv.y, 0.f);
            r1.y = fmaxf(acc[1][1] + bv.y, 0.f);
            r1.z = fmaxf(acc[1][2] + bv.y, 0.f);
            r1.w = fmaxf(acc[1][3] + bv.y, 0.f);
            *(float4*)&sH2[o0][w0]     = r0;
            *(float4*)&sH2[o0 + 1][w0] = r1;
        }
        __syncthreads();
    }

    // ================= conv3: 64 -> 32, relu, scatter =================
    {
        const int og3 = t & 15, wg3 = (t >> 4) & 7, cs3 = t >> 7;
        const int o0 = 2 * og3, w0 = 2 * wg3;
        const int u3 = t & 127;
        float acc[2][2] = {};
        #pragma unroll 4
        for (int j = 0; j < 16; ++j) {
            const int cc = 16 * cs3 + j;
            const float2 wv = *(const float2*)&sW[4096 + cc * 32 + o0];
            const float2 xi = *(const float2*)&sH2[cc][w0];
            acc[0][0] += xi.x * wv.x; acc[0][1] += xi.y * wv.x;
            acc[1][0] += xi.x * wv.y; acc[1][1] += xi.y * wv.y;
        }
        if (cs3 > 0) {
            float4 v;
            v.x = acc[0][0]; v.y = acc[0][1];
            v.z = acc[1][0]; v.w = acc[1][1];
            *(float4*)&sW[(cs3 - 1) * 512 + u3 * 4] = v;
        }
        __syncthreads();
        if (cs3 == 0) {
            #pragma unroll
            for (int s = 0; s < 3; ++s) {
                const float4 v = *(const float4*)&sW[s * 512 + u3 * 4];
                acc[0][0] += v.x; acc[0][1] += v.y;
                acc[1][0] += v.z; acc[1][1] += v.w;
            }
            const float2 bv = *(const float2*)&cb3[o0];
            #pragma unroll
            for (int oj = 0; oj < 2; ++oj) {
                const int kbase = (((o0 + oj) * 8 + zi) * 8 + yi) * 15;
                const float bj = oj ? bv.y : bv.x;
                #pragma unroll
                for (int wj = 0; wj < 2; ++wj) {
                    const int w = w0 + wj;
                    if (w < 15)
                        fvecT[(size_t)(kbase + w) * 8 + b] =
                            fmaxf(acc[oj][wj] + bj, 0.f);
                }
            }
        }
    }
}

// ---------------------------------------------------------------------------
// K2: column-panel streamer, inner loop R13-exact; KSPLIT 96->80 (KCH=384)
// -> 1200 blocks, one more step down the measured stream-count curve
// (3600:189us, 1800:155, 1440:144). sF = 12 KB LDS.
// ---------------------------------------------------------------------------
__global__ __launch_bounds__(64) void k2_stream(
    const float* __restrict__ hw,
    const float* __restrict__ fvecT,
    const float* __restrict__ coord,
    float* __restrict__ partial)
{
    __shared__ float zpart[512];
    __shared__ float sF[KCH * 8];  // this k-chunk's fvec, all 8 batches (12 KB)
    const int t = threadIdx.x;     // 0..63
    const int kbase = blockIdx.y * KCH;

    #pragma unroll
    for (int r = 0; r < 8; ++r) zpart[t * 8 + r] = 0.f;
    {
        const float4* fsrc = (const float4*)(fvecT + (size_t)kbase * 8);
        float4* fdst = (float4*)sF;
        #pragma unroll
        for (int p = 0; p < 12; ++p) fdst[t + 64 * p] = fsrc[t + 64 * p];
    }
    __syncthreads();

    const int jw = blockIdx.x * 512;
    const int j0 = jw + 4 * t;

    float accA[8][4] = {}, accB[8][4] = {};
    const float* hp = hw + (size_t)kbase * NWCOL + j0;

    #pragma unroll 4
    for (int kk = 0; kk < KCH; ++kk) {
        const float4 hA = *(const float4*)hp;
        const float4 hB = *(const float4*)(hp + 256);
        hp += NWCOL;
        const float4 f0 = *(const float4*)&sF[kk * 8];      // broadcast
        const float4 f1 = *(const float4*)&sF[kk * 8 + 4];  // broadcast
        const float fv[8] = {f0.x, f0.y, f0.z, f0.w, f1.x, f1.y, f1.z, f1.w};
        #pragma unroll
        for (int b = 0; b < 8; ++b) {
            accA[b][0] += fv[b] * hA.x;
            accA[b][1] += fv[b] * hA.y;
            accA[b][2] += fv[b] * hA.z;
            accA[b][3] += fv[b] * hA.w;
            accB[b][0] += fv[b] * hB.x;
            accB[b][1] += fv[b] * hB.y;
            accB[b][2] += fv[b] * hB.z;
            accB[b][3] += fv[b] * hB.w;
        }
    }

    // fold z[b,f] for both col-quads (same output cols cq.., different f)
    const int fA = 8 * blockIdx.x + (t >> 4);
    const int fB = fA + 4;
    const int i3A = fA / 40, qA = fA - 40 * i3A;
    const int i3B = fB / 40, qB = fB - 40 * i3B;
    const float freqA = __expf((float)qA * LN1024_OVER_39);
    const float freqB = __expf((float)qB * LN1024_OVER_39);
    const int cq = 4 * (t & 15);

    #pragma unroll
    for (int b = 0; b < 8; ++b) {
        const float zvA = coord[b * 3 + i3A] * freqA;
        const float zvB = coord[b * 3 + i3B] * freqB;
        #pragma unroll
        for (int e = 0; e < 4; ++e)
            atomicAdd(&zpart[b * 64 + cq + e],
                      zvA * accA[b][e] + zvB * accB[b][e]);
    }
    __syncthreads();

    const int bid = blockIdx.x + 15 * blockIdx.y;
    float4* pp = (float4*)(partial + (size_t)bid * 512);
    pp[t]      = ((const float4*)zpart)[t];
    pp[t + 64] = ((const float4*)zpart)[t + 64];
}

// ---------------------------------------------------------------------------
// K2bc: fused reduce + MLP tail (threadFenceReduction pattern).
// Blocks 0..63: reduce partial[1200][512] -> z1, fence, bump counter.
// Block 64: stage MLP weights (overlaps reduction), spin on counter,
// then run the K3 body. 65 blocks co-resident trivially -> no deadlock;
// z1 values are order-independent -> deterministic.
// ---------------------------------------------------------------------------
__global__ __launch_bounds__(512) void k2bc_tail(
    const float* __restrict__ partial, float* __restrict__ z1,
    int* __restrict__ counter,
    const float* __restrict__ coord, const float* __restrict__ hb,
    const float* __restrict__ w1, const float* __restrict__ b1,
    const float* __restrict__ w2, const float* __restrict__ b2,
    const float* __restrict__ wo, const float* __restrict__ bo,
    float* __restrict__ out)
{
    __shared__ float shb[7680];  // 30 KB (blocks<64 reuse first 2 KB as scratch)
    __shared__ float sw1[4096];  // 16 KB
    __shared__ float sw2[4096];  // 16 KB
    __shared__ float swo[192];
    __shared__ float sz[8][64];
    __shared__ float s2[8][64];
    __shared__ float sfreq[40];
    __shared__ float sc[24];
    const int t = threadIdx.x;

    if (blockIdx.x < 64) {
        // ---- reduction block ----
        float* s = shb;  // 512-float scratch
        const int o = blockIdx.x * 8 + (t & 7);
        float sum = 0.f;
        for (int blk = t >> 3; blk < NBLK; blk += 64)
            sum += partial[(size_t)blk * 512 + o];
        s[t] = sum;
        __syncthreads();
        if (t < 8) {
            float tot = 0.f;
            #pragma unroll
            for (int i = 0; i < 64; ++i) tot += s[t + 8 * i];
            z1[blockIdx.x * 8 + t] = tot;
            __threadfence();  // writer's own store -> device scope
        }
        __syncthreads();      // all 8 fences done before the bump
        if (t == 0) atomicAdd(counter, 1);
        return;
    }

    // ---- block 64: stage weights while reductions run ----
    #pragma unroll
    for (int p = 0; p < 4; ++p) {
        const int idx = t + 512 * p;
        if (idx < 1920) ((float4*)shb)[idx] = ((const float4*)hb)[idx];
    }
    ((float4*)sw1)[t]       = ((const float4*)w1)[t];
    ((float4*)sw1)[t + 512] = ((const float4*)w1)[t + 512];
    ((float4*)sw2)[t]       = ((const float4*)w2)[t];
    ((float4*)sw2)[t + 512] = ((const float4*)w2)[t + 512];
    if (t < 48) ((float4*)swo)[t] = ((const float4*)wo)[t];
    if (t < 40) sfreq[t] = __expf((float)t * LN1024_OVER_39);
    if (t < 24) sc[t] = coord[t];

    // ---- wait for all 64 reduction blocks ----
    if (t == 0) {
        while (atomicCAS(counter, 64, 64) != 64) { }
    }
    __syncthreads();
    __threadfence();  // acquire side before reading z1

    const int b = t >> 6, c = t & 63;

    float a = z1[t];
    #pragma unroll
    for (int i = 0; i < 3; ++i) {
        const float cv = sc[b * 3 + i];
        #pragma unroll 8
        for (int q = 0; q < 40; ++q)
            a += cv * sfreq[q] * shb[(i * 40 + q) * 64 + c];
    }
    sz[b][c] = a;  // no activation on modulated layer 0
    __syncthreads();

    float a1 = b1[c];
    #pragma unroll 8
    for (int cc = 0; cc < 64; ++cc) a1 += sz[b][cc] * sw1[cc * 64 + c];
    s2[b][c] = fmaxf(a1, 0.f);
    __syncthreads();

    float a2 = b2[c];
    #pragma unroll 8
    for (int cc = 0; cc < 64; ++cc) a2 += s2[b][cc] * sw2[cc * 64 + c];
    sz[b][c] = fmaxf(a2, 0.f);
    __syncthreads();

    if (t < 24) {
        const int bb = t / 3, i = t - bb * 3;
        float o = bo[i];
        #pragma unroll 8
        for (int cc = 0; cc < 64; ++cc) o += sz[bb][cc] * swo[cc * 3 + i];
        out[t] = o;
    }
}

// ---------------------------------------------------------------------------
extern "C" void kernel_launch(void* const* d_in, const int* in_sizes, int n_in,
                              void* d_out, int out_size, void* d_ws, size_t ws_size,
                              hipStream_t stream)
{
    const float* coord = (const float*)d_in[0];
    const float* feat0 = (const float*)d_in[1];
    const float* cw1 = (const float*)d_in[2];
    const float* cb1 = (const float*)d_in[3];
    const float* cw2 = (const float*)d_in[4];
    const float* cb2 = (const float*)d_in[5];
    const float* cw3 = (const float*)d_in[6];
    const float* cb3 = (const float*)d_in[7];
    const float* hw  = (const float*)d_in[8];
    const float* hb  = (const float*)d_in[9];
    const float* w1  = (const float*)d_in[10];
    const float* b1  = (const float*)d_in[11];
    const float* w2  = (const float*)d_in[12];
    const float* b2  = (const float*)d_in[13];
    const float* wo  = (const float*)d_in[14];
    const float* bo  = (const float*)d_in[15];
    float* out = (float*)d_out;

    float* fvecT   = (float*)d_ws;                  // 30720*8 floats = 983 KB
    float* partial = fvecT + (size_t)KTOT * 8;      // 1200*512 floats = 2.46 MB
    float* z1      = partial + (size_t)NBLK * 512;  // 512 floats
    int*   counter = (int*)(z1 + 512);

    k1_conv<<<dim3(8, 8, 8), 512, 0, stream>>>(feat0, cw1, cb1, cw2, cb2,
                                               cw3, cb3, fvecT, counter);
    k2_stream<<<dim3(15, KSPLIT), 64, 0, stream>>>(hw, fvecT, coord, partial);
    k2bc_tail<<<65, 512, 0, stream>>>(partial, z1, counter, coord, hb,
                                      w1, b1, w2, b2, wo, bo, out);
}